// Round 3
// baseline (26705.991 us; speedup 1.0000x reference)
//
#include <hip/hip_runtime.h>

using u16 = unsigned short;
using u32 = unsigned int;
using bf16x8 = __attribute__((ext_vector_type(8))) short;
using f32x4  = __attribute__((ext_vector_type(4))) float;

// ---------------- workspace layout (bytes) ----------------
// xu  : [T=512][B=64][4096] bf16 (packed cols n' = hc*4 + gate)      256 MiB
// xb  : [B*T*F] bf16 copy of x                                        64 MiB
// UT  : [4096][1024] bf16  (UT[n'][f] = U_g[f][hc])                    8 MiB
// VT  : [4096][1024] bf16                                              8 MiB
// bp  : [4096] fp32 packed bias
// h hi/lo double buffers: 4 x [64][1024] bf16
// bar : barrier counters (16 group lines x 128B, master, epoch)
static constexpr size_t XU_OFF = 0;
static constexpr size_t XU_BYTES = (size_t)512 * 64 * 4096 * 2;
static constexpr size_t XB_OFF = XU_OFF + XU_BYTES;
static constexpr size_t XB_BYTES = (size_t)64 * 512 * 1024 * 2;
static constexpr size_t UT_OFF = XB_OFF + XB_BYTES;
static constexpr size_t WT_BYTES = (size_t)4096 * 1024 * 2;
static constexpr size_t VT_OFF = UT_OFF + WT_BYTES;
static constexpr size_t BP_OFF = VT_OFF + WT_BYTES;
static constexpr size_t BP_BYTES = 4096 * 4;
static constexpr size_t HH_OFF = BP_OFF + BP_BYTES;          // hi0, hi1, lo0, lo1
static constexpr size_t H_BYTES = (size_t)64 * 1024 * 2;     // 128 KiB each
static constexpr size_t BAR_OFF = HH_OFF + 4 * H_BYTES;
static constexpr size_t BAR_BYTES = 4096;
// bar u32 layout: grp g at [g*32]; master at [512+32]; epoch at [512+64]

__device__ __forceinline__ float bf2f(u32 u) {
    return __uint_as_float(u << 16);
}
__device__ __forceinline__ u16 f2bf(float f) {
    u32 u = __float_as_uint(f);
    u32 r = (u + 0x7FFFu + ((u >> 16) & 1u)) >> 16;
    return (u16)r;
}

// ------------- x fp32 -> bf16 -------------
__global__ void cvt_x_kernel(const float4* __restrict__ x, uint2* __restrict__ xb) {
    int i = blockIdx.x * 256 + threadIdx.x;
#pragma unroll
    for (int k = 0; k < 8; ++k) {
        int idx = i + k * 1048576;
        float4 v = x[idx];
        uint2 o;
        o.x = (u32)f2bf(v.x) | ((u32)f2bf(v.y) << 16);
        o.y = (u32)f2bf(v.z) | ((u32)f2bf(v.w) << 16);
        xb[idx] = o;
    }
}

// ------------- repack: U/V fp32 -> bf16, K-contiguous, gate-interleaved columns -------------
__global__ void repack_kernel(const float* U0, const float* U1, const float* U2, const float* U3,
                              const float* V0, const float* V1, const float* V2, const float* V3,
                              u16* UT, u16* VT) {
    __shared__ u16 tile[64][65];
    int bx  = blockIdx.x;
    int mat = bx >> 8;
    int rem = bx & 255;
    int tf = rem >> 4, th = rem & 15;
    int f0 = tf * 64, h0 = th * 64;
    const float* srcs[8] = {U0, U1, U2, U3, V0, V1, V2, V3};
    const float* s = srcs[mat];
    u16* d = (mat < 4) ? UT : VT;
    int g = mat & 3;
    int c = threadIdx.x & 63;
    int r = threadIdx.x >> 6;
#pragma unroll
    for (int i = 0; i < 16; ++i) {
        int fr = r + i * 4;
        tile[fr][c] = f2bf(s[(size_t)(f0 + fr) * 1024 + h0 + c]);
    }
    __syncthreads();
#pragma unroll
    for (int i = 0; i < 16; ++i) {
        int hcl = r + i * 4;
        d[(size_t)((h0 + hcl) * 4 + g) * 1024 + f0 + c] = tile[c][hcl];
    }
}

// ------------- bias pack -------------
__global__ void bias_kernel(const float* b0, const float* b1, const float* b2, const float* b3,
                            float* bp) {
    int n = blockIdx.x * 256 + threadIdx.x;
    int g = n & 3, hc = n >> 2;
    const float* bs[4] = {b0, b1, b2, b3};
    bp[n] = bs[g][hc];
}

// ------------- xU GEMM -------------
__global__ void __launch_bounds__(256) gemm_xu_kernel(const u16* __restrict__ xb,
                                                      const u16* __restrict__ UT,
                                                      const float* __restrict__ bp,
                                                      u16* __restrict__ xu) {
    int bx = blockIdx.x;
    int nt = bx & 31, mt = bx >> 5;
    int tid = threadIdx.x;
    int lane = tid & 63, wv = tid >> 6;
    int wm = wv & 1, wn = wv >> 1;
    int l15 = lane & 15, quad = lane >> 4;

    int arow0 = mt * 128 + wm * 64 + l15;
    int brow0 = nt * 128 + wn * 64 + l15;

    f32x4 acc[4][4];
#pragma unroll
    for (int i = 0; i < 4; ++i)
#pragma unroll
        for (int j = 0; j < 4; ++j) acc[i][j] = f32x4{0.f, 0.f, 0.f, 0.f};

    float biasv[4];
#pragma unroll
    for (int j = 0; j < 4; ++j) biasv[j] = bp[brow0 + 16 * j];

    const u16* abase = xb + (size_t)arow0 * 1024;
    const u16* bbase = UT + (size_t)brow0 * 1024;

#pragma unroll 2
    for (int kk = 0; kk < 32; ++kk) {
        int ko = kk * 32 + quad * 8;
        bf16x8 af[4], bfv[4];
#pragma unroll
        for (int i = 0; i < 4; ++i)
            af[i] = *(const bf16x8*)(abase + (size_t)i * 16 * 1024 + ko);
#pragma unroll
        for (int j = 0; j < 4; ++j)
            bfv[j] = *(const bf16x8*)(bbase + (size_t)j * 16 * 1024 + ko);
#pragma unroll
        for (int i = 0; i < 4; ++i)
#pragma unroll
            for (int j = 0; j < 4; ++j)
                acc[i][j] = __builtin_amdgcn_mfma_f32_16x16x32_bf16(af[i], bfv[j], acc[i][j], 0, 0, 0);
    }

#pragma unroll
    for (int i = 0; i < 4; ++i) {
        int rbase = mt * 128 + wm * 64 + 16 * i + quad * 4;
#pragma unroll
        for (int j = 0; j < 4; ++j) {
            int col = brow0 + 16 * j;
            float bj = biasv[j];
#pragma unroll
            for (int rg = 0; rg < 4; ++rg) {
                int r = rbase + rg;
                int b_i = r >> 9, t_i = r & 511;
                xu[((size_t)(t_i * 64 + b_i) << 12) + col] = f2bf(acc[i][j][rg] + bj);
            }
        }
    }
}

// ------------- recurrent scan with custom hierarchical grid barrier -------------
// 256 blocks x 256 threads, 1 block/CU. Block bx owns packed cols [16bx,16bx+16).
// Barrier: 16 groups x 16 blocks -> 16 parallel arrive chains, master chain of 16,
// monotonic epoch publish; agent-scope atomics. Replaces gg.sync()'s 256-long
// serialized RMW chain (~38us/step measured).
__global__ void __launch_bounds__(256) lstm_rec_kernel(const u16* __restrict__ xu,
                                                       const u16* __restrict__ VT,
                                                       u16* __restrict__ hhi0,
                                                       u16* __restrict__ hhi1,
                                                       u16* __restrict__ hlo0,
                                                       u16* __restrict__ hlo1,
                                                       u32* __restrict__ bar,
                                                       float* __restrict__ out) {
    constexpr int VS_STRIDE = 1032;
    __shared__ u16  Vs[16 * VS_STRIDE];
    __shared__ float zs[64 * 17];

    int bx = blockIdx.x;
    int tid = threadIdx.x;
    int lane = tid & 63, wv = tid >> 6;
    int l15 = lane & 15, quad = lane >> 4;
    int b_row = tid >> 2, hcl = tid & 3;

    u32* grpCnt  = bar + (bx >> 4) * 32;   // 16 blocks per group, 128B apart
    u32* master  = bar + 512 + 32;
    u32* epoch   = bar + 512 + 64;

    {   // stage V-slice
        const u16* src = VT + (size_t)bx * 16 * 1024;
#pragma unroll
        for (int it = 0; it < 8; ++it) {
            int id = it * 256 + tid;
            int row = id >> 7;
            int c8  = id & 127;
            *(uint4*)&Vs[row * VS_STRIDE + c8 * 8] = *(const uint4*)(src + row * 1024 + c8 * 8);
        }
    }
    __syncthreads();

    const u16* brow = Vs + (size_t)l15 * VS_STRIDE + quad * 8;
    float c = 0.f;
    float h = 0.f;

    for (int t = 0; t < 512; ++t) {
        const u16* hi_in  = (t & 1) ? hhi1 : hhi0;
        const u16* lo_in  = (t & 1) ? hlo1 : hlo0;
        u16*       hi_out = (t & 1) ? hhi0 : hhi1;
        u16*       lo_out = (t & 1) ? hlo0 : hlo1;

        uint2 xraw = *(const uint2*)(xu + ((size_t)(t * 64 + b_row) << 12) + bx * 16 + hcl * 4);

        f32x4 acc = f32x4{0.f, 0.f, 0.f, 0.f};
        const u16* arow_hi = hi_in + (size_t)(wv * 16 + l15) * 1024 + quad * 8;
        const u16* arow_lo = lo_in + (size_t)(wv * 16 + l15) * 1024 + quad * 8;
#pragma unroll
        for (int kk = 0; kk < 32; ++kk) {
            bf16x8 ah = *(const bf16x8*)(arow_hi + kk * 32);
            bf16x8 al = *(const bf16x8*)(arow_lo + kk * 32);
            bf16x8 b  = *(const bf16x8*)(brow + kk * 32);
            acc = __builtin_amdgcn_mfma_f32_16x16x32_bf16(ah, b, acc, 0, 0, 0);
            acc = __builtin_amdgcn_mfma_f32_16x16x32_bf16(al, b, acc, 0, 0, 0);
        }
#pragma unroll
        for (int rg = 0; rg < 4; ++rg)
            zs[(wv * 16 + quad * 4 + rg) * 17 + l15] = acc[rg];
        __syncthreads();

        float z0 = zs[b_row * 17 + hcl * 4 + 0] + bf2f(xraw.x & 0xFFFFu);
        float z1 = zs[b_row * 17 + hcl * 4 + 1] + bf2f(xraw.x >> 16);
        float z2 = zs[b_row * 17 + hcl * 4 + 2] + bf2f(xraw.y & 0xFFFFu);
        float z3 = zs[b_row * 17 + hcl * 4 + 3] + bf2f(xraw.y >> 16);

        float it_ = 1.f / (1.f + __expf(-z0));
        float ft_ = 1.f / (1.f + __expf(-z1));
        float gt_ = tanhf(z2);
        float ot_ = tanhf(z3);   // reference uses tanh for output gate
        c = ft_ * c + it_ * gt_;
        h = ot_ * tanhf(c);

        u32 hh = f2bf(h);
        float hlo = h - bf2f(hh);
        int hidx = b_row * 1024 + bx * 4 + hcl;
        hi_out[hidx] = (u16)hh;
        lo_out[hidx] = f2bf(hlo);

        // ---- hierarchical grid barrier ----
        __threadfence();            // release: push h stores to device scope
        __syncthreads();            // all threads' fences precede the arrive
        if (tid == 0) {
            u32 tgt = (u32)t + 1u;
            u32 prev = __hip_atomic_fetch_add(grpCnt, 1u, __ATOMIC_ACQ_REL,
                                              __HIP_MEMORY_SCOPE_AGENT);
            if (prev == tgt * 16u - 1u) {
                u32 p2 = __hip_atomic_fetch_add(master, 1u, __ATOMIC_ACQ_REL,
                                                __HIP_MEMORY_SCOPE_AGENT);
                if (p2 == tgt * 16u - 1u)
                    __hip_atomic_store(epoch, tgt, __ATOMIC_RELEASE,
                                       __HIP_MEMORY_SCOPE_AGENT);
            }
            while (__hip_atomic_load(epoch, __ATOMIC_ACQUIRE,
                                     __HIP_MEMORY_SCOPE_AGENT) < tgt)
                __builtin_amdgcn_s_sleep(1);
        }
        __syncthreads();            // acquire (tid0's buffer_inv) covers the CU
    }

    out[(size_t)b_row * 1024 + bx * 4 + hcl] = h;
}

extern "C" void kernel_launch(void* const* d_in, const int* in_sizes, int n_in,
                              void* d_out, int out_size, void* d_ws, size_t ws_size,
                              hipStream_t stream) {
    char* ws = (char*)d_ws;
    const float* x = (const float*)d_in[0];
    const float *U[4], *V[4], *b[4];
    for (int g = 0; g < 4; ++g) {
        U[g] = (const float*)d_in[1 + 3 * g];
        V[g] = (const float*)d_in[2 + 3 * g];
        b[g] = (const float*)d_in[3 + 3 * g];
    }
    u16*   xu = (u16*)(ws + XU_OFF);
    u16*   xb = (u16*)(ws + XB_OFF);
    u16*   UT = (u16*)(ws + UT_OFF);
    u16*   VT = (u16*)(ws + VT_OFF);
    float* bp = (float*)(ws + BP_OFF);
    u16*   hhi0 = (u16*)(ws + HH_OFF);
    u16*   hhi1 = (u16*)(ws + HH_OFF + H_BYTES);
    u16*   hlo0 = (u16*)(ws + HH_OFF + 2 * H_BYTES);
    u16*   hlo1 = (u16*)(ws + HH_OFF + 3 * H_BYTES);
    u32*   bar  = (u32*)(ws + BAR_OFF);
    float* out = (float*)d_out;

    // zero h double-buffers + barrier counters (ws poisoned before every call)
    hipMemsetAsync(ws + HH_OFF, 0, 4 * H_BYTES + BAR_BYTES, stream);

    cvt_x_kernel<<<4096, 256, 0, stream>>>((const float4*)x, (uint2*)xb);
    repack_kernel<<<2048, 256, 0, stream>>>(U[0], U[1], U[2], U[3],
                                            V[0], V[1], V[2], V[3], UT, VT);
    bias_kernel<<<16, 256, 0, stream>>>(b[0], b[1], b[2], b[3], bp);
    gemm_xu_kernel<<<8192, 256, 0, stream>>>(xb, UT, bp, xu);

    void* args[] = {(void*)&xu, (void*)&VT, (void*)&hhi0, (void*)&hhi1,
                    (void*)&hlo0, (void*)&hlo1, (void*)&bar, (void*)&out};
    hipLaunchCooperativeKernel((const void*)lstm_rec_kernel, dim3(256), dim3(256),
                               args, 0, stream);
}

// Round 4
// 7338.341 us; speedup vs baseline: 3.6392x; 3.6392x over previous
//
#include <hip/hip_runtime.h>

using u16 = unsigned short;
using u32 = unsigned int;
using u64 = unsigned long long;
using bf16x8 = __attribute__((ext_vector_type(8))) short;
using f32x4  = __attribute__((ext_vector_type(4))) float;

// ---------------- workspace layout (bytes) ----------------
static constexpr size_t XU_OFF = 0;
static constexpr size_t XU_BYTES = (size_t)512 * 64 * 4096 * 2;      // 256 MiB
static constexpr size_t XB_OFF = XU_OFF + XU_BYTES;
static constexpr size_t XB_BYTES = (size_t)64 * 512 * 1024 * 2;      // 64 MiB
static constexpr size_t UT_OFF = XB_OFF + XB_BYTES;
static constexpr size_t WT_BYTES = (size_t)4096 * 1024 * 2;          // 8 MiB
static constexpr size_t VT_OFF = UT_OFF + WT_BYTES;
static constexpr size_t BP_OFF = VT_OFF + WT_BYTES;
static constexpr size_t BP_BYTES = 4096 * 4;
static constexpr size_t HH_OFF = BP_OFF + BP_BYTES;                  // hi0, hi1, lo0, lo1
static constexpr size_t H_BYTES = (size_t)64 * 1024 * 2;             // 128 KiB each
static constexpr size_t BAR_OFF = HH_OFF + 4 * H_BYTES;
static constexpr size_t BAR_BYTES = 4096;
// bar u32 layout: grp g at [g*32]; master at [512+32]; epoch at [512+64]

__device__ __forceinline__ float bf2f(u32 u) {
    return __uint_as_float(u << 16);
}
__device__ __forceinline__ u16 f2bf(float f) {
    u32 u = __float_as_uint(f);
    u32 r = (u + 0x7FFFu + ((u >> 16) & 1u)) >> 16;
    return (u16)r;
}

// ------------- x fp32 -> bf16 -------------
__global__ void cvt_x_kernel(const float4* __restrict__ x, uint2* __restrict__ xb) {
    int i = blockIdx.x * 256 + threadIdx.x;
#pragma unroll
    for (int k = 0; k < 8; ++k) {
        int idx = i + k * 1048576;
        float4 v = x[idx];
        uint2 o;
        o.x = (u32)f2bf(v.x) | ((u32)f2bf(v.y) << 16);
        o.y = (u32)f2bf(v.z) | ((u32)f2bf(v.w) << 16);
        xb[idx] = o;
    }
}

// ------------- repack: U/V fp32 -> bf16, K-contiguous, gate-interleaved columns -------------
__global__ void repack_kernel(const float* U0, const float* U1, const float* U2, const float* U3,
                              const float* V0, const float* V1, const float* V2, const float* V3,
                              u16* UT, u16* VT) {
    __shared__ u16 tile[64][65];
    int bx  = blockIdx.x;
    int mat = bx >> 8;
    int rem = bx & 255;
    int tf = rem >> 4, th = rem & 15;
    int f0 = tf * 64, h0 = th * 64;
    const float* srcs[8] = {U0, U1, U2, U3, V0, V1, V2, V3};
    const float* s = srcs[mat];
    u16* d = (mat < 4) ? UT : VT;
    int g = mat & 3;
    int c = threadIdx.x & 63;
    int r = threadIdx.x >> 6;
#pragma unroll
    for (int i = 0; i < 16; ++i) {
        int fr = r + i * 4;
        tile[fr][c] = f2bf(s[(size_t)(f0 + fr) * 1024 + h0 + c]);
    }
    __syncthreads();
#pragma unroll
    for (int i = 0; i < 16; ++i) {
        int hcl = r + i * 4;
        d[(size_t)((h0 + hcl) * 4 + g) * 1024 + f0 + c] = tile[c][hcl];
    }
}

// ------------- bias pack -------------
__global__ void bias_kernel(const float* b0, const float* b1, const float* b2, const float* b3,
                            float* bp) {
    int n = blockIdx.x * 256 + threadIdx.x;
    int g = n & 3, hc = n >> 2;
    const float* bs[4] = {b0, b1, b2, b3};
    bp[n] = bs[g][hc];
}

// ------------- xU GEMM -------------
__global__ void __launch_bounds__(256) gemm_xu_kernel(const u16* __restrict__ xb,
                                                      const u16* __restrict__ UT,
                                                      const float* __restrict__ bp,
                                                      u16* __restrict__ xu) {
    int bx = blockIdx.x;
    int nt = bx & 31, mt = bx >> 5;
    int tid = threadIdx.x;
    int lane = tid & 63, wv = tid >> 6;
    int wm = wv & 1, wn = wv >> 1;
    int l15 = lane & 15, quad = lane >> 4;

    int arow0 = mt * 128 + wm * 64 + l15;
    int brow0 = nt * 128 + wn * 64 + l15;

    f32x4 acc[4][4];
#pragma unroll
    for (int i = 0; i < 4; ++i)
#pragma unroll
        for (int j = 0; j < 4; ++j) acc[i][j] = f32x4{0.f, 0.f, 0.f, 0.f};

    float biasv[4];
#pragma unroll
    for (int j = 0; j < 4; ++j) biasv[j] = bp[brow0 + 16 * j];

    const u16* abase = xb + (size_t)arow0 * 1024;
    const u16* bbase = UT + (size_t)brow0 * 1024;

#pragma unroll 2
    for (int kk = 0; kk < 32; ++kk) {
        int ko = kk * 32 + quad * 8;
        bf16x8 af[4], bfv[4];
#pragma unroll
        for (int i = 0; i < 4; ++i)
            af[i] = *(const bf16x8*)(abase + (size_t)i * 16 * 1024 + ko);
#pragma unroll
        for (int j = 0; j < 4; ++j)
            bfv[j] = *(const bf16x8*)(bbase + (size_t)j * 16 * 1024 + ko);
#pragma unroll
        for (int i = 0; i < 4; ++i)
#pragma unroll
            for (int j = 0; j < 4; ++j)
                acc[i][j] = __builtin_amdgcn_mfma_f32_16x16x32_bf16(af[i], bfv[j], acc[i][j], 0, 0, 0);
    }

#pragma unroll
    for (int i = 0; i < 4; ++i) {
        int rbase = mt * 128 + wm * 64 + 16 * i + quad * 4;
#pragma unroll
        for (int j = 0; j < 4; ++j) {
            int col = brow0 + 16 * j;
            float bj = biasv[j];
#pragma unroll
            for (int rg = 0; rg < 4; ++rg) {
                int r = rbase + rg;
                int b_i = r >> 9, t_i = r & 511;
                xu[((size_t)(t_i * 64 + b_i) << 12) + col] = f2bf(acc[i][j][rg] + bj);
            }
        }
    }
}

// ------------- recurrent scan: write-through h + relaxed-poll barrier -------------
// 256 blocks x 256 threads, 1 block/CU. Block bx owns packed cols [16bx,16bx+16).
// Visibility scheme (replaces fence-based sync, which cost ~40-50us/step in
// buffer_wbl2 + per-poll buffer_inv):
//   - h stores: agent-scope RELAXED atomic stores (sc1 write-through, no dirty L2)
//   - release: s_waitcnt vmcnt(0) per wave (stores ack'd at coherence point)
//   - arrive: hierarchical 16x16 relaxed fetch_add chains; epoch publish
//   - poll: RELAXED loads (no cache ops); ONE acquire load (single buffer_inv)
//     after success; h reads stay cached vector loads (L2 dedups per XCD)
//   - t==0 skips the MFMA (h==0), so h buffers never need pre-zeroing
__global__ void __launch_bounds__(256) lstm_rec_kernel(const u16* __restrict__ xu,
                                                       const u16* __restrict__ VT,
                                                       u16* __restrict__ hhi0,
                                                       u16* __restrict__ hhi1,
                                                       u16* __restrict__ hlo0,
                                                       u16* __restrict__ hlo1,
                                                       u32* __restrict__ bar,
                                                       float* __restrict__ out) {
    constexpr int VS_STRIDE = 1032;
    __shared__ u16  Vs[16 * VS_STRIDE];
    __shared__ float zs[64 * 17];

    int bx = blockIdx.x;
    int tid = threadIdx.x;
    int lane = tid & 63, wv = tid >> 6;
    int l15 = lane & 15, quad = lane >> 4;
    int b_row = tid >> 2, hcl = tid & 3;

    u32* grpCnt  = bar + (bx >> 4) * 32;   // 16 blocks per group, 128B apart
    u32* master  = bar + 512 + 32;
    u32* epoch   = bar + 512 + 64;

    {   // stage V-slice
        const u16* src = VT + (size_t)bx * 16 * 1024;
#pragma unroll
        for (int it = 0; it < 8; ++it) {
            int id = it * 256 + tid;
            int row = id >> 7;
            int c8  = id & 127;
            *(uint4*)&Vs[row * VS_STRIDE + c8 * 8] = *(const uint4*)(src + row * 1024 + c8 * 8);
        }
    }
    __syncthreads();

    const u16* brow = Vs + (size_t)l15 * VS_STRIDE + quad * 8;
    float c = 0.f;
    float h = 0.f;
    int hidx = b_row * 1024 + bx * 4 + hcl;

    uint2 xraw = *(const uint2*)(xu + ((size_t)(0 * 64 + b_row) << 12) + bx * 16 + hcl * 4);

    for (int t = 0; t < 512; ++t) {
        const u16* hi_in  = (t & 1) ? hhi1 : hhi0;
        const u16* lo_in  = (t & 1) ? hlo1 : hlo0;
        u16*       hi_out = (t & 1) ? hhi0 : hhi1;
        u16*       lo_out = (t & 1) ? hlo0 : hlo1;

        f32x4 acc = f32x4{0.f, 0.f, 0.f, 0.f};
        if (t) {   // t==0: h is zero -> z = xu only (and h buffers are unwritten)
            const u16* arow_hi = hi_in + (size_t)(wv * 16 + l15) * 1024 + quad * 8;
            const u16* arow_lo = lo_in + (size_t)(wv * 16 + l15) * 1024 + quad * 8;
#pragma unroll
            for (int kk = 0; kk < 32; ++kk) {
                bf16x8 ah = *(const bf16x8*)(arow_hi + kk * 32);
                bf16x8 al = *(const bf16x8*)(arow_lo + kk * 32);
                bf16x8 b  = *(const bf16x8*)(brow + kk * 32);
                acc = __builtin_amdgcn_mfma_f32_16x16x32_bf16(ah, b, acc, 0, 0, 0);
                acc = __builtin_amdgcn_mfma_f32_16x16x32_bf16(al, b, acc, 0, 0, 0);
            }
        }
#pragma unroll
        for (int rg = 0; rg < 4; ++rg)
            zs[(wv * 16 + quad * 4 + rg) * 17 + l15] = acc[rg];
        __syncthreads();

        float z0 = zs[b_row * 17 + hcl * 4 + 0] + bf2f(xraw.x & 0xFFFFu);
        float z1 = zs[b_row * 17 + hcl * 4 + 1] + bf2f(xraw.x >> 16);
        float z2 = zs[b_row * 17 + hcl * 4 + 2] + bf2f(xraw.y & 0xFFFFu);
        float z3 = zs[b_row * 17 + hcl * 4 + 3] + bf2f(xraw.y >> 16);

        float it_ = 1.f / (1.f + __expf(-z0));
        float ft_ = 1.f / (1.f + __expf(-z1));
        float gt_ = tanhf(z2);
        float ot_ = tanhf(z3);   // reference uses tanh for output gate
        c = ft_ * c + it_ * gt_;
        h = ot_ * tanhf(c);

        // write-through h (hi + lo planes), agent scope, relaxed
        u32 hh = f2bf(h);
        float hlo = h - bf2f(hh);
        __hip_atomic_store(hi_out + hidx, (u16)hh, __ATOMIC_RELAXED,
                           __HIP_MEMORY_SCOPE_AGENT);
        __hip_atomic_store(lo_out + hidx, f2bf(hlo), __ATOMIC_RELAXED,
                           __HIP_MEMORY_SCOPE_AGENT);

        // every wave drains its stores to the coherence point (release)
        asm volatile("s_waitcnt vmcnt(0)" ::: "memory");

        // prefetch next xu into registers: survives the inv, hides HBM miss
        int tn = (t < 511) ? t + 1 : 511;
        uint2 xnext = *(const uint2*)(xu + ((size_t)(tn * 64 + b_row) << 12) + bx * 16 + hcl * 4);

        __syncthreads();           // all waves of the block have released h
        if (tid == 0) {
            u32 tgt = (u32)t + 1u;
            u32 prev = __hip_atomic_fetch_add(grpCnt, 1u, __ATOMIC_RELAXED,
                                              __HIP_MEMORY_SCOPE_AGENT);
            if (prev == tgt * 16u - 1u) {
                u32 p2 = __hip_atomic_fetch_add(master, 1u, __ATOMIC_RELAXED,
                                                __HIP_MEMORY_SCOPE_AGENT);
                if (p2 == tgt * 16u - 1u)
                    __hip_atomic_store(epoch, tgt, __ATOMIC_RELAXED,
                                       __HIP_MEMORY_SCOPE_AGENT);
            }
            while (__hip_atomic_load(epoch, __ATOMIC_RELAXED,
                                     __HIP_MEMORY_SCOPE_AGENT) < tgt)
                __builtin_amdgcn_s_sleep(1);
            // single acquire: one buffer_inv for this CU (L1 + XCD L2 lines)
            (void)__hip_atomic_load(epoch, __ATOMIC_ACQUIRE,
                                    __HIP_MEMORY_SCOPE_AGENT);
        }
        __syncthreads();
        xraw = xnext;
    }

    out[hidx] = h;
}

extern "C" void kernel_launch(void* const* d_in, const int* in_sizes, int n_in,
                              void* d_out, int out_size, void* d_ws, size_t ws_size,
                              hipStream_t stream) {
    char* ws = (char*)d_ws;
    const float* x = (const float*)d_in[0];
    const float *U[4], *V[4], *b[4];
    for (int g = 0; g < 4; ++g) {
        U[g] = (const float*)d_in[1 + 3 * g];
        V[g] = (const float*)d_in[2 + 3 * g];
        b[g] = (const float*)d_in[3 + 3 * g];
    }
    u16*   xu = (u16*)(ws + XU_OFF);
    u16*   xb = (u16*)(ws + XB_OFF);
    u16*   UT = (u16*)(ws + UT_OFF);
    u16*   VT = (u16*)(ws + VT_OFF);
    float* bp = (float*)(ws + BP_OFF);
    u16*   hhi0 = (u16*)(ws + HH_OFF);
    u16*   hhi1 = (u16*)(ws + HH_OFF + H_BYTES);
    u16*   hlo0 = (u16*)(ws + HH_OFF + 2 * H_BYTES);
    u16*   hlo1 = (u16*)(ws + HH_OFF + 3 * H_BYTES);
    u32*   bar  = (u32*)(ws + BAR_OFF);
    float* out = (float*)d_out;

    // only the barrier counters need zeroing (h init handled by t==0 skip)
    hipMemsetAsync(ws + BAR_OFF, 0, BAR_BYTES, stream);

    cvt_x_kernel<<<4096, 256, 0, stream>>>((const float4*)x, (uint2*)xb);
    repack_kernel<<<2048, 256, 0, stream>>>(U[0], U[1], U[2], U[3],
                                            V[0], V[1], V[2], V[3], UT, VT);
    bias_kernel<<<16, 256, 0, stream>>>(b[0], b[1], b[2], b[3], bp);
    gemm_xu_kernel<<<8192, 256, 0, stream>>>(xb, UT, bp, xu);

    void* args[] = {(void*)&xu, (void*)&VT, (void*)&hhi0, (void*)&hhi1,
                    (void*)&hlo0, (void*)&hlo1, (void*)&bar, (void*)&out};
    hipLaunchCooperativeKernel((const void*)lstm_rec_kernel, dim3(256), dim3(256),
                               args, 0, stream);
}